// Round 5
// baseline (3192.029 us; speedup 1.0000x reference)
//
#include <hip/hip_runtime.h>
#include <math.h>

#define T_STEPS 4096
#define NB 16          // batch
#define NH 256         // hidden
#define BH (NB * NH)   // 4096 floats per time step
#define DT_STEP 0.1f

// ---------------- expm via Taylor series ----------------
__global__ __launch_bounds__(1024) void k_init_S(const float* __restrict__ A,
                                                 float* __restrict__ S) {
    int idx = blockIdx.x * 1024 + threadIdx.x;
    int i = idx >> 8, j = idx & 255;
    S[idx] = A[idx] + (i == j ? 1.0f : 0.0f);
}

__global__ __launch_bounds__(256) void k_expm_term(const float* __restrict__ Pprev,
                                                   const float* __restrict__ A,
                                                   float* __restrict__ Pnew,
                                                   float* __restrict__ S,
                                                   float invk) {
    __shared__ float prow[256];
    int i = blockIdx.x, j = threadIdx.x;
    prow[j] = Pprev[i * 256 + j];
    __syncthreads();
    float acc = 0.f;
#pragma unroll 8
    for (int m = 0; m < 256; ++m) acc = fmaf(prow[m], A[m * 256 + j], acc);
    float v = acc * invk;
    Pnew[i * 256 + j] = v;
    S[i * 256 + j] += v;
}

// ---------------- row-blocked GEMM (unchanged, works) ----------------
__global__ __launch_bounds__(256) void k_gemm_rows(const float* __restrict__ X,
                                                   const float* __restrict__ Wm,
                                                   const float* __restrict__ bias,
                                                   float* __restrict__ Out) {
    __shared__ float4 xs4[16][64];
    const int tid = threadIdx.x;
    const long r0 = (long)blockIdx.x * 16;
    float* xs = (float*)xs4;
#pragma unroll
    for (int rr = 0; rr < 16; ++rr) xs[rr * 256 + tid] = X[(r0 + rr) * 256 + tid];
    __syncthreads();

    float acc[16];
#pragma unroll
    for (int rr = 0; rr < 16; ++rr) acc[rr] = 0.f;

    const float4* wrow = (const float4*)(Wm + tid * 256);
    for (int d4 = 0; d4 < 64; ++d4) {
        float4 w = wrow[d4];
#pragma unroll
        for (int rr = 0; rr < 16; ++rr) {
            float4 xv = xs4[rr][d4];
            acc[rr] = fmaf(w.x, xv.x, acc[rr]);
            acc[rr] = fmaf(w.y, xv.y, acc[rr]);
            acc[rr] = fmaf(w.z, xv.z, acc[rr]);
            acc[rr] = fmaf(w.w, xv.w, acc[rr]);
        }
    }
    float b = bias[tid];
#pragma unroll
    for (int rr = 0; rr < 16; ++rr) Out[(r0 + rr) * 256 + tid] = acc[rr] + b;
}

// DPP butterfly add: x + x[lane ^ k] for k in {1,2,8} via quad_perm / row_ror:8
template <int CTRL>
__device__ __forceinline__ float dpp_add(float x) {
    int yi = __builtin_amdgcn_mov_dpp(__float_as_int(x), CTRL, 0xF, 0xF, true);
    return x + __int_as_float(yi);
}

// W fragment as 128 NAMED scalars (no arrays -> no scratch-demotion risk)
#define ALLJK(OP) \
  OP(0,0) OP(0,1) OP(0,2) OP(0,3) OP(0,4) OP(0,5) OP(0,6) OP(0,7) \
  OP(1,0) OP(1,1) OP(1,2) OP(1,3) OP(1,4) OP(1,5) OP(1,6) OP(1,7) \
  OP(2,0) OP(2,1) OP(2,2) OP(2,3) OP(2,4) OP(2,5) OP(2,6) OP(2,7) \
  OP(3,0) OP(3,1) OP(3,2) OP(3,3) OP(3,4) OP(3,5) OP(3,6) OP(3,7)

#define DW(j,k) float w##j##_##k##_x, w##j##_##k##_y, w##j##_##k##_z, w##j##_##k##_w;

#define LW(j,k) { float4 t_ = ((const float4*)(Wexp + (i0 + j) * 256 + (c << 5)))[k]; \
                  w##j##_##k##_x = t_.x; w##j##_##k##_y = t_.y;                        \
                  w##j##_##k##_z = t_.z; w##j##_##k##_w = t_.w; }

#define DACC(j) float acc##j##_x = 0.f, acc##j##_y = 0.f, acc##j##_z = 0.f, acc##j##_w = 0.f;

#define FK(j,k,HV) acc##j##_x = fmaf(w##j##_##k##_x, HV.x, acc##j##_x); \
                   acc##j##_y = fmaf(w##j##_##k##_y, HV.y, acc##j##_y); \
                   acc##j##_z = fmaf(w##j##_##k##_z, HV.z, acc##j##_z); \
                   acc##j##_w = fmaf(w##j##_##k##_w, HV.w, acc##j##_w);

#define KBLK(k) { float4 hv_ = *(const float4*)(rb + roff + ha##k);    \
                  FK(0,k,hv_) FK(1,k,hv_) FK(2,k,hv_) FK(3,k,hv_) }

#define DHA(k) const int ha##k = (c << 7) | ((((k) + c) & 7) << 4);

#define RED(j) float p##j = (acc##j##_x + acc##j##_y) + (acc##j##_z + acc##j##_w); \
               p##j = dpp_add<0xB1>(p##j);                                         \
               p##j = dpp_add<0x4E>(p##j);                                         \
               p##j = dpp_add<0x128>(p##j);

// lgkm-only barrier: no vmcnt(0) drain -> u-prefetch / hidden-store stay in flight
#define LBAR() asm volatile("s_waitcnt lgkmcnt(0)\n\ts_barrier" ::: "memory")

// ---------------- sequential scan: one block (CU) per batch element ----------------
// 512 threads = 8 waves, grid = 16 blocks -> exactly 1 block/CU, 2 waves/SIMD.
// amdgpu_waves_per_eu(2,2) pins the allocator's occupancy target to the TRUE
// occupancy -> 256-VGPR budget -> 128 W floats stay register-resident.
// Lane l: K-chunk c = bits{0,1,3} (32 floats), row-quad q = bits{2,4,5}.
// h double-buffered in LDS, bank-rotation swizzle (conflict-free 8-way bcast).
// K-reduce = DPP xor1/xor2/xor8. One lgkm-barrier per step.
__global__ __launch_bounds__(512)
__attribute__((amdgpu_waves_per_eu(2, 2)))
void k_scan5(const float* __restrict__ u,
             const float* Wexp,   // no restrict: forbid remat
             float* hidden,       // no restrict: forbid remat
             float* __restrict__ hfin) {
    const int b = blockIdx.x;
    const int tid = threadIdx.x;
    const int w = tid >> 6;
    const int l = tid & 63;
    const int c = (l & 3) | ((l & 8) >> 1);          // chunk 0..7  (lane bits 0,1,3)
    const int q = ((l >> 2) & 1) | ((l >> 3) & 6);   // row-quad 0..7 (lane bits 2,4,5)
    const int i0 = (w << 5) | (q << 2);              // first of this thread's 4 rows
    const bool wr = ((l & 8) == 0);                  // writer lanes (c < 4)
    const int cc = c & 3;                            // component owned by writer lane

    __shared__ float4 hbuf[2][64];                   // h[256] double-buffered, swizzled

    ALLJK(DW)
    ALLJK(LW)

    DHA(0) DHA(1) DHA(2) DHA(3) DHA(4) DHA(5) DHA(6) DHA(7)
    const int waddr = (w << 7) | (((q + w) & 7) << 4) | (cc << 2);

    ((float*)hbuf)[tid] = 0.0f;                      // zero both buffers (512 floats)

    const float* up = u + b * NH + i0 + cc;
    float* hp = hidden + b * NH + i0 + cc;

    float u_cur = 0.f, u_nxt = 0.f, hval = 0.f;
    if (wr) {
        u_cur = up[0];
        u_nxt = up[BH];
    }
    LBAR();

    const char* rb = (const char*)hbuf;
    char* wb = (char*)hbuf;
    int roff = 0;

    for (int t = 0; t < T_STEPS; ++t) {
        float u_n2 = 0.f;
        if (wr && t + 2 < T_STEPS) u_n2 = up[(size_t)(t + 2) * BH];

        DACC(0) DACC(1) DACC(2) DACC(3)
        KBLK(0) KBLK(1) KBLK(2) KBLK(3)
        KBLK(4) KBLK(5) KBLK(6) KBLK(7)

        RED(0) RED(1) RED(2) RED(3)
        float y = (c & 2) ? ((c & 1) ? p3 : p2) : ((c & 1) ? p1 : p0);

        if (wr) {
            float xa = u_cur - y;
            xa = fminf(fmaxf(xa, -9.0f), 9.0f);
            float E = __expf(2.0f * xa);
            float th = (E - 1.0f) * __builtin_amdgcn_rcpf(E + 1.0f);
            hval = fmaf(DT_STEP, th, hval);
            *(float*)(wb + (roff ^ 1024) + waddr) = hval;   // next h buffer
            hp[(size_t)t * BH] = hval;                      // stage for output GEMM
        }
        u_cur = u_nxt;
        u_nxt = u_n2;
        roff ^= 1024;
        LBAR();
    }
    if (wr) hfin[b * NH + i0 + cc] = hval;
}

extern "C" void kernel_launch(void* const* d_in, const int* in_sizes, int n_in,
                              void* d_out, int out_size, void* d_ws, size_t ws_size,
                              hipStream_t stream) {
    const float* x     = (const float*)d_in[0];  // [T,B,D]
    const float* U_w   = (const float*)d_in[1];  // [H,D]
    const float* U_b   = (const float*)d_in[2];  // [H]
    const float* W_log = (const float*)d_in[3];  // [H,H]
    const float* c_w   = (const float*)d_in[4];  // [O,H]
    const float* c_b   = (const float*)d_in[5];  // [O]

    float* out    = (float*)d_out;
    float* hidden = out;                          // stage hidden in d_out, then in-place GEMM
    float* hfin   = out + (long)T_STEPS * BH;     // second output chunk

    float* ws = (float*)d_ws;
    float* S  = ws;                // 65536 floats: Wexp accumulator
    float* Pa = ws + 65536;
    float* Pb = ws + 2 * 65536;
    float* u  = ws + 3 * 65536;    // 16,777,216 floats

    // Wexp = expm(W_log), Taylor K=9 (||W_log||_2 ~ 0.32 -> remainder ~1e-9)
    k_init_S<<<64, 1024, 0, stream>>>(W_log, S);
    const float* prev = W_log;
    float* cur = Pa;
    for (int k = 2; k <= 9; ++k) {
        k_expm_term<<<256, 256, 0, stream>>>(prev, W_log, cur, S, 1.0f / (float)k);
        prev = cur;
        cur = (cur == Pa) ? Pb : Pa;
    }

    // u = x @ U_w^T + U_b
    k_gemm_rows<<<4096, 256, 0, stream>>>(x, U_w, U_b, u);

    // sequential recurrence, hidden -> d_out
    k_scan5<<<NB, 512, 0, stream>>>(u, S, hidden, hfin);

    // out = hidden @ c_w^T + c_b, in place
    k_gemm_rows<<<4096, 256, 0, stream>>>(hidden, c_w, c_b, hidden);
}

// Round 6
// 3186.861 us; speedup vs baseline: 1.0016x; 1.0016x over previous
//
#include <hip/hip_runtime.h>
#include <math.h>

#define T_STEPS 4096
#define NB 16          // batch
#define NH 256         // hidden
#define BH (NB * NH)   // 4096 floats per time step
#define DT_STEP 0.1f

// ---------------- expm via Taylor series ----------------
__global__ __launch_bounds__(1024) void k_init_S(const float* __restrict__ A,
                                                 float* __restrict__ S) {
    int idx = blockIdx.x * 1024 + threadIdx.x;
    int i = idx >> 8, j = idx & 255;
    S[idx] = A[idx] + (i == j ? 1.0f : 0.0f);
}

__global__ __launch_bounds__(256) void k_expm_term(const float* __restrict__ Pprev,
                                                   const float* __restrict__ A,
                                                   float* __restrict__ Pnew,
                                                   float* __restrict__ S,
                                                   float invk) {
    __shared__ float prow[256];
    int i = blockIdx.x, j = threadIdx.x;
    prow[j] = Pprev[i * 256 + j];
    __syncthreads();
    float acc = 0.f;
#pragma unroll 8
    for (int m = 0; m < 256; ++m) acc = fmaf(prow[m], A[m * 256 + j], acc);
    float v = acc * invk;
    Pnew[i * 256 + j] = v;
    S[i * 256 + j] += v;
}

// ---------------- row-blocked GEMM (unchanged, works) ----------------
__global__ __launch_bounds__(256) void k_gemm_rows(const float* __restrict__ X,
                                                   const float* __restrict__ Wm,
                                                   const float* __restrict__ bias,
                                                   float* __restrict__ Out) {
    __shared__ float4 xs4[16][64];
    const int tid = threadIdx.x;
    const long r0 = (long)blockIdx.x * 16;
    float* xs = (float*)xs4;
#pragma unroll
    for (int rr = 0; rr < 16; ++rr) xs[rr * 256 + tid] = X[(r0 + rr) * 256 + tid];
    __syncthreads();

    float acc[16];
#pragma unroll
    for (int rr = 0; rr < 16; ++rr) acc[rr] = 0.f;

    const float4* wrow = (const float4*)(Wm + tid * 256);
    for (int d4 = 0; d4 < 64; ++d4) {
        float4 w = wrow[d4];
#pragma unroll
        for (int rr = 0; rr < 16; ++rr) {
            float4 xv = xs4[rr][d4];
            acc[rr] = fmaf(w.x, xv.x, acc[rr]);
            acc[rr] = fmaf(w.y, xv.y, acc[rr]);
            acc[rr] = fmaf(w.z, xv.z, acc[rr]);
            acc[rr] = fmaf(w.w, xv.w, acc[rr]);
        }
    }
    float b = bias[tid];
#pragma unroll
    for (int rr = 0; rr < 16; ++rr) Out[(r0 + rr) * 256 + tid] = acc[rr] + b;
}

// DPP butterfly add: x + x[lane ^ k] for k in {1,2,8} via quad_perm / row_ror:8
template <int CTRL>
__device__ __forceinline__ float dpp_add(float x) {
    int yi = __builtin_amdgcn_mov_dpp(__float_as_int(x), CTRL, 0xF, 0xF, true);
    return x + __int_as_float(yi);
}

// ---------------- sequential scan: one block (CU) per batch element ----------------
// 1024 threads = 16 waves = 4 waves/SIMD (2x the latency hiding of the 512 version).
// Wave r owns rows 16r..16r+15, full K=256 in-wave (no cross-wave reduce).
// Lane l: K-chunk c = bits{0,1,3} (32 floats), row-slot q = bits{2,4,5}.
// Per thread: 2 rows x 32-float W chunk = 64 floats (fits the 128-VGPR budget
// from __launch_bounds__(1024,4) -> no spill/stream pressure).
// h double-buffered in LDS, bank-rotation swizzle (8 addrs -> 32 banks,
// 8-way broadcast, conflict-free). K-reduce = DPP xor1/xor2/xor8.
// One __syncthreads per step.
__global__ __launch_bounds__(1024, 4)
void k_scan6(const float* __restrict__ u,
             const float* __restrict__ Wexp,
             float* __restrict__ hidden,
             float* __restrict__ hfin) {
    const int b = blockIdx.x;
    const int tid = threadIdx.x;
    const int r = tid >> 6;                          // wave 0..15
    const int l = tid & 63;
    const int c = (l & 3) | ((l & 8) >> 1);          // chunk 0..7  (lane bits 0,1,3)
    const int q = ((l >> 2) & 1) | ((l >> 3) & 6);   // slot 0..7   (lane bits 2,4,5)
    const int i0 = (r << 4) | (q << 1);              // first of this thread's 2 rows
    const bool wr = ((l & 2) == 0) && ((l & 8) == 0); // writer lanes: c < 2
    const int cc = l & 1;                            // which of the 2 rows
    const int irow = i0 | cc;                        // writer's row

    __shared__ float4 hbuf[2][64];                   // h[256] double-buffered, swizzled

    // W[i0][32c..] and W[i0+1][32c..] -> 16 float4 = 64 VGPRs
    float4 wv0[8], wv1[8];
    {
        const float4* wp0 = (const float4*)(Wexp + (size_t)i0 * 256 + (c << 5));
        const float4* wp1 = (const float4*)(Wexp + (size_t)(i0 + 1) * 256 + (c << 5));
#pragma unroll
        for (int k = 0; k < 8; ++k) { wv0[k] = wp0[k]; wv1[k] = wp1[k]; }
    }

    // swizzled read offsets: float4 f=8c+k4 stored at 128c + 16*((k4+c)&7)
    int ha[8];
#pragma unroll
    for (int k = 0; k < 8; ++k) ha[k] = (c << 7) | (((k + c) & 7) << 4);
    // writer's store addr for h[irow]
    const int fc = irow >> 5;
    const int fk = (irow >> 2) & 7;
    const int waddr = (fc << 7) | (((fk + fc) & 7) << 4) | ((irow & 3) << 2);

    if (tid < 512) ((float*)hbuf)[tid] = 0.0f;       // zero both buffers

    const float* up = u + b * NH + irow;
    float* hp = hidden + b * NH + irow;

    float u_cur = 0.f, u_nxt = 0.f, hval = 0.f;
    if (wr) {
        u_cur = up[0];
        u_nxt = up[BH];
    }
    __syncthreads();

    const char* base = (const char*)hbuf;
    int roff = 0;

    for (int t = 0; t < T_STEPS; ++t) {
        float u_n2 = 0.f;
        if (wr && t + 2 < T_STEPS) u_n2 = up[(size_t)(t + 2) * BH];

        float a0x = 0.f, a0y = 0.f, a0z = 0.f, a0w = 0.f;
        float a1x = 0.f, a1y = 0.f, a1z = 0.f, a1w = 0.f;
#pragma unroll
        for (int k = 0; k < 8; ++k) {
            float4 hv = *(const float4*)(base + roff + ha[k]);
            a0x = fmaf(wv0[k].x, hv.x, a0x);
            a0y = fmaf(wv0[k].y, hv.y, a0y);
            a0z = fmaf(wv0[k].z, hv.z, a0z);
            a0w = fmaf(wv0[k].w, hv.w, a0w);
            a1x = fmaf(wv1[k].x, hv.x, a1x);
            a1y = fmaf(wv1[k].y, hv.y, a1y);
            a1z = fmaf(wv1[k].z, hv.z, a1z);
            a1w = fmaf(wv1[k].w, hv.w, a1w);
        }
        float p0 = (a0x + a0y) + (a0z + a0w);
        float p1 = (a1x + a1y) + (a1z + a1w);
        p0 = dpp_add<0xB1>(p0); p0 = dpp_add<0x4E>(p0); p0 = dpp_add<0x128>(p0);
        p1 = dpp_add<0xB1>(p1); p1 = dpp_add<0x4E>(p1); p1 = dpp_add<0x128>(p1);
        float y = cc ? p1 : p0;

        if (wr) {
            float xa = u_cur - y;
            xa = fminf(fmaxf(xa, -9.0f), 9.0f);
            float E = __expf(2.0f * xa);
            float th = (E - 1.0f) * __builtin_amdgcn_rcpf(E + 1.0f);
            hval = fmaf(DT_STEP, th, hval);
            *(float*)((char*)hbuf + (roff ^ 1024) + waddr) = hval;  // next h buffer
            hp[(size_t)t * BH] = hval;                              // stage for GEMM
        }
        u_cur = u_nxt;
        u_nxt = u_n2;
        roff ^= 1024;
        __syncthreads();
    }
    if (wr) hfin[b * NH + irow] = hval;
}

extern "C" void kernel_launch(void* const* d_in, const int* in_sizes, int n_in,
                              void* d_out, int out_size, void* d_ws, size_t ws_size,
                              hipStream_t stream) {
    const float* x     = (const float*)d_in[0];  // [T,B,D]
    const float* U_w   = (const float*)d_in[1];  // [H,D]
    const float* U_b   = (const float*)d_in[2];  // [H]
    const float* W_log = (const float*)d_in[3];  // [H,H]
    const float* c_w   = (const float*)d_in[4];  // [O,H]
    const float* c_b   = (const float*)d_in[5];  // [O]

    float* out    = (float*)d_out;
    float* hidden = out;                          // stage hidden in d_out, then in-place GEMM
    float* hfin   = out + (long)T_STEPS * BH;     // second output chunk

    float* ws = (float*)d_ws;
    float* S  = ws;                // 65536 floats: Wexp accumulator
    float* Pa = ws + 65536;
    float* Pb = ws + 2 * 65536;
    float* u  = ws + 3 * 65536;    // 16,777,216 floats

    // Wexp = expm(W_log), Taylor K=9 (||W_log||_2 ~ 0.32 -> remainder ~1e-9)
    k_init_S<<<64, 1024, 0, stream>>>(W_log, S);
    const float* prev = W_log;
    float* cur = Pa;
    for (int k = 2; k <= 9; ++k) {
        k_expm_term<<<256, 256, 0, stream>>>(prev, W_log, cur, S, 1.0f / (float)k);
        prev = cur;
        cur = (cur == Pa) ? Pb : Pa;
    }

    // u = x @ U_w^T + U_b
    k_gemm_rows<<<4096, 256, 0, stream>>>(x, U_w, U_b, u);

    // sequential recurrence, hidden -> d_out
    k_scan6<<<NB, 1024, 0, stream>>>(u, S, hidden, hfin);

    // out = hidden @ c_w^T + c_b, in place
    k_gemm_rows<<<4096, 256, 0, stream>>>(hidden, c_w, c_b, hidden);
}

// Round 7
// 2334.883 us; speedup vs baseline: 1.3671x; 1.3649x over previous
//
#include <hip/hip_runtime.h>
#include <math.h>

#define T_STEPS 4096
#define NB 16          // batch
#define NH 256         // hidden
#define BH (NB * NH)   // 4096 floats per time step
#define DT_STEP 0.1f

typedef __attribute__((ext_vector_type(8))) short short8;
typedef __attribute__((ext_vector_type(4))) float f32x4;

// ---------------- expm via Taylor series ----------------
__global__ __launch_bounds__(1024) void k_init_S(const float* __restrict__ A,
                                                 float* __restrict__ S) {
    int idx = blockIdx.x * 1024 + threadIdx.x;
    int i = idx >> 8, j = idx & 255;
    S[idx] = A[idx] + (i == j ? 1.0f : 0.0f);
}

__global__ __launch_bounds__(256) void k_expm_term(const float* __restrict__ Pprev,
                                                   const float* __restrict__ A,
                                                   float* __restrict__ Pnew,
                                                   float* __restrict__ S,
                                                   float invk) {
    __shared__ float prow[256];
    int i = blockIdx.x, j = threadIdx.x;
    prow[j] = Pprev[i * 256 + j];
    __syncthreads();
    float acc = 0.f;
#pragma unroll 8
    for (int m = 0; m < 256; ++m) acc = fmaf(prow[m], A[m * 256 + j], acc);
    float v = acc * invk;
    Pnew[i * 256 + j] = v;
    S[i * 256 + j] += v;
}

// ---------------- row-blocked GEMM (unchanged, works) ----------------
__global__ __launch_bounds__(256) void k_gemm_rows(const float* __restrict__ X,
                                                   const float* __restrict__ Wm,
                                                   const float* __restrict__ bias,
                                                   float* __restrict__ Out) {
    __shared__ float4 xs4[16][64];
    const int tid = threadIdx.x;
    const long r0 = (long)blockIdx.x * 16;
    float* xs = (float*)xs4;
#pragma unroll
    for (int rr = 0; rr < 16; ++rr) xs[rr * 256 + tid] = X[(r0 + rr) * 256 + tid];
    __syncthreads();

    float acc[16];
#pragma unroll
    for (int rr = 0; rr < 16; ++rr) acc[rr] = 0.f;

    const float4* wrow = (const float4*)(Wm + tid * 256);
    for (int d4 = 0; d4 < 64; ++d4) {
        float4 w = wrow[d4];
#pragma unroll
        for (int rr = 0; rr < 16; ++rr) {
            float4 xv = xs4[rr][d4];
            acc[rr] = fmaf(w.x, xv.x, acc[rr]);
            acc[rr] = fmaf(w.y, xv.y, acc[rr]);
            acc[rr] = fmaf(w.z, xv.z, acc[rr]);
            acc[rr] = fmaf(w.w, xv.w, acc[rr]);
        }
    }
    float b = bias[tid];
#pragma unroll
    for (int rr = 0; rr < 16; ++rr) Out[(r0 + rr) * 256 + tid] = acc[rr] + b;
}

// ---------------- MFMA scan: one block (CU) per batch ----------------
// y = Wexp@h = h + E@h with E = Wexp - I (|E|~0.01). h kept exact in f32
// registers; only E·h goes through bf16 MFMA (16x16x32, M=1 real row).
// 16 waves: wave w owns output cols 16w..16w+15 (B-frag = E[n][k] in 32 VGPRs,
// resident). h exchanged via LDS in A-fragment-linear layout:
//   byte(kt, e) = kt*1152 + e*16 + (e>>4)*32   (e = lane index of the frag)
// Real A rows: m = lane&15 == 0 -> only 4 lanes/wave read (exec-masked,
// conflict-free); other lanes keep zero frags. Writers = lanes 0..15
// (col = 16w + l), pack (col,col+1) bf16 pairs via DPP + v_cvt_pk_bf16_f32.
// One barrier/step; u prefetched 2 deep.
__global__ __launch_bounds__(1024, 4)
void k_scan_mfma(const float* __restrict__ u,
                 const float* __restrict__ S,   // Wexp (f32)
                 float* __restrict__ hidden,
                 float* __restrict__ hfin) {
    const int b   = blockIdx.x;
    const int tid = threadIdx.x;
    const int w   = tid >> 6;            // wave = n-tile
    const int l   = tid & 63;
    const int n   = (w << 4) | (l & 15); // E row this lane serves (B-frag col)
    const int kg  = l >> 4;              // k-group 0..3

    __shared__ uint4 lds4[1152];         // 2 x (8 kt x 1152B) = 18432 B
    char* lds = (char*)lds4;
    for (int i = tid; i < 1152; i += 1024) lds4[i] = uint4{0, 0, 0, 0};

    // ---- B-fragments: E[n][kt*32+kg*8 .. +7] as packed bf16 (resident) ----
    union Frag { unsigned int u[4]; short8 v; };
    Frag ef[8];
#pragma unroll
    for (int kt = 0; kt < 8; ++kt) {
        const int k0 = kt * 32 + kg * 8;
        const float* sp = S + (size_t)n * 256 + k0;
        float e[8];
#pragma unroll
        for (int j = 0; j < 8; ++j)
            e[j] = sp[j] - ((n == k0 + j) ? 1.0f : 0.0f);
#pragma unroll
        for (int r2 = 0; r2 < 4; ++r2) {
            unsigned int pk;
            asm volatile("v_cvt_pk_bf16_f32 %0, %1, %2"
                         : "=v"(pk) : "v"(e[2 * r2]), "v"(e[2 * r2 + 1]));
            ef[kt].u[r2] = pk;
        }
    }

    // ---- A-fragments: persistent, zero except the 4 data lanes ----
    Frag af[8];
#pragma unroll
    for (int kt = 0; kt < 8; ++kt) {
        af[kt].u[0] = 0; af[kt].u[1] = 0; af[kt].u[2] = 0; af[kt].u[3] = 0;
    }
    const bool areal = ((l & 15) == 0);
    const int  abase = l * 16 + kg * 32;       // + kt*1152 + dbuf

    // ---- writer lanes: one h element each (col = n) ----
    const bool wr  = (l < 16);
    const int  col = (w << 4) | l;             // == n for l<16
    const int  wg  = (col >> 3) & 3;
    const int  wby = (col >> 5) * 1152 + wg * 288 + ((col & 7) >> 1) * 4;

    const float* up = u + (size_t)b * NH + col;
    float* hp = hidden + (size_t)b * NH + col;

    float hval = 0.f, u_cur = 0.f, u_nxt = 0.f;
    if (wr) {
        u_cur = up[0];
        u_nxt = up[BH];
    }
    __syncthreads();

    int roff = 0;                               // read buffer offset (0 / 9216)
    for (int t = 0; t < T_STEPS; ++t) {
        float u_n2 = 0.f;
        if (wr && t + 2 < T_STEPS) u_n2 = up[(size_t)(t + 2) * BH];

        if (areal) {
#pragma unroll
            for (int kt = 0; kt < 8; ++kt)
                af[kt].v = *(const short8*)(lds + roff + kt * 1152 + abase);
        }

        f32x4 acc = {0.f, 0.f, 0.f, 0.f};
#pragma unroll
        for (int kt = 0; kt < 8; ++kt)
            acc = __builtin_amdgcn_mfma_f32_16x16x32_bf16(af[kt].v, ef[kt].v, acc, 0, 0, 0);

        if (wr) {
            float y  = acc[0];                  // row m=0, col = l
            float xa = (u_cur - hval) - y;      // u - (h + E h)
            // tanh(x) = 1 - 2/(e^{2x}+1); graceful at +/-inf, no clamp needed
            float E2 = __expf(2.0f * xa);
            float th = fmaf(-2.0f, __builtin_amdgcn_rcpf(E2 + 1.0f), 1.0f);
            hval = fmaf(DT_STEP, th, hval);
            hp[(size_t)t * BH] = hval;
            // pack (col, col+1) -> u32, store into next A-buffer
            int nb = __builtin_amdgcn_mov_dpp(__float_as_int(hval), 0xB1, 0xF, 0xF, true);
            if ((l & 1) == 0) {
                unsigned int pk;
                asm volatile("v_cvt_pk_bf16_f32 %0, %1, %2"
                             : "=v"(pk) : "v"(hval), "v"(__int_as_float(nb)));
                *(unsigned int*)(lds + (roff ^ 9216) + wby) = pk;
            }
        }
        u_cur = u_nxt;
        u_nxt = u_n2;
        roff ^= 9216;
        __syncthreads();
    }
    if (wr) hfin[(size_t)b * NH + col] = hval;
}

extern "C" void kernel_launch(void* const* d_in, const int* in_sizes, int n_in,
                              void* d_out, int out_size, void* d_ws, size_t ws_size,
                              hipStream_t stream) {
    const float* x     = (const float*)d_in[0];  // [T,B,D]
    const float* U_w   = (const float*)d_in[1];  // [H,D]
    const float* U_b   = (const float*)d_in[2];  // [H]
    const float* W_log = (const float*)d_in[3];  // [H,H]
    const float* c_w   = (const float*)d_in[4];  // [O,H]
    const float* c_b   = (const float*)d_in[5];  // [O]

    float* out    = (float*)d_out;
    float* hidden = out;                          // stage hidden in d_out, then in-place GEMM
    float* hfin   = out + (long)T_STEPS * BH;     // second output chunk

    float* ws = (float*)d_ws;
    float* S  = ws;                // 65536 floats: Wexp accumulator
    float* Pa = ws + 65536;
    float* Pb = ws + 2 * 65536;
    float* u  = ws + 3 * 65536;    // 16,777,216 floats

    // Wexp = expm(W_log), Taylor K=9 (||W_log||_2 ~ 0.32 -> remainder ~1e-9)
    k_init_S<<<64, 1024, 0, stream>>>(W_log, S);
    const float* prev = W_log;
    float* cur = Pa;
    for (int k = 2; k <= 9; ++k) {
        k_expm_term<<<256, 256, 0, stream>>>(prev, W_log, cur, S, 1.0f / (float)k);
        prev = cur;
        cur = (cur == Pa) ? Pb : Pa;
    }

    // u = x @ U_w^T + U_b
    k_gemm_rows<<<4096, 256, 0, stream>>>(x, U_w, U_b, u);

    // sequential recurrence (MFMA), hidden -> d_out
    k_scan_mfma<<<NB, 1024, 0, stream>>>(u, S, hidden, hfin);

    // out = hidden @ c_w^T + c_b, in place
    k_gemm_rows<<<4096, 256, 0, stream>>>(hidden, c_w, c_b, hidden);
}